// Round 1
// 299.147 us; speedup vs baseline: 1.1146x; 1.1146x over previous
//
#include <hip/hip_runtime.h>
#include <hip/hip_bf16.h>

typedef __bf16 bf16;
typedef unsigned short u16;
typedef unsigned int u32;
typedef __attribute__((ext_vector_type(8))) __bf16 bf16x8;
typedef __attribute__((ext_vector_type(4))) unsigned short u16x4;
typedef __attribute__((ext_vector_type(4))) float f32x4;

#define B_  4
#define S_  2048
#define D_  1024
#define H_  16
#define HD_ 64

// 0.125 * log2(e): folded into q so softmax is exp2(acc) directly
#define QSCALE 0.18033688f

__device__ inline u16 bf16_bits(float f) {
  bf16 h = (bf16)f;
  return __builtin_bit_cast(u16, h);
}

__device__ __forceinline__ void glds16(const bf16* g, bf16* s) {
  __builtin_amdgcn_global_load_lds(
      (const __attribute__((address_space(1))) void*)g,
      (__attribute__((address_space(3))) void*)s, 16, 0, 0);
}

#define MEMFENCE() asm volatile("" ::: "memory")
#define BARRIER_RAW() __builtin_amdgcn_s_barrier()
#define LGKM0() asm volatile("s_waitcnt lgkmcnt(0)" ::: "memory")
#define VMCNT(n) asm volatile("s_waitcnt vmcnt(" #n ")" ::: "memory")

// ---------------- converters ----------------
__global__ void cvt_x(const float* __restrict__ in, bf16* __restrict__ out, long n) {
  long i = ((long)blockIdx.x * 256 + threadIdx.x) * 8;
  if (i < n) {
    f32x4 a = *(const f32x4*)(in + i);
    f32x4 b = *(const f32x4*)(in + i + 4);
    bf16x8 v;
#pragma unroll
    for (int j = 0; j < 4; ++j) { v[j] = (bf16)a[j]; v[4 + j] = (bf16)b[j]; }
    *(bf16x8*)(out + i) = v;
  }
}

// f32 [K][N] -> bf16 [N][K] (transpose + convert)
__global__ void cvt_w(const float* __restrict__ in, bf16* __restrict__ out,
                      int K, int N) {
  __shared__ float tile[32][33];
  int n0 = blockIdx.x * 32, k0 = blockIdx.y * 32;
  int x = threadIdx.x, y = threadIdx.y;  // block (32,8)
#pragma unroll
  for (int i = 0; i < 32; i += 8)
    tile[y + i][x] = in[(long)(k0 + y + i) * N + (n0 + x)];
  __syncthreads();
#pragma unroll
  for (int i = 0; i < 32; i += 8)
    out[(long)(n0 + y + i) * K + (k0 + x)] = (bf16)tile[x][y + i];
}

// ---------------- m97-structure GEMM core (128x128 tile) --------------------
// Kept for the attention-out projection (grid 512 blocks there).
template <typename TC>
__launch_bounds__(256)
__global__ void gemm128(const bf16* __restrict__ A, const bf16* __restrict__ Bt,
                        TC* __restrict__ C, int M, int N, int K) {
  __shared__ __attribute__((aligned(16))) bf16 As[8][512];
  __shared__ __attribute__((aligned(16))) bf16 Bs[8][512];
  int t = threadIdx.x;
  int w = t >> 6, lane = t & 63;
  int wr = w >> 1, wc = w & 1;
  int fr = lane & 15, fq = lane >> 4;
  long m0 = (long)blockIdx.y * 128, n0 = (long)blockIdx.x * 128;
  f32x4 acc[4][4] = {};
  const bf16* ag = A  + (m0 + (2 * w) * 16 + fr) * (long)K + fq * 8;
  const bf16* bg = Bt + (n0 + (2 * w) * 16 + fr) * (long)K + fq * 8;
  bf16* al0 = &As[2 * w][0];
  bf16* al1 = &As[2 * w + 1][0];
  bf16* bl0 = &Bs[2 * w][0];
  bf16* bl1 = &Bs[2 * w + 1][0];
  const long K16 = 16 * (long)K;
  for (int k0 = 0; k0 < K; k0 += 32) {
    __syncthreads();
    glds16(ag + k0, al0);
    glds16(ag + k0 + K16, al1);
    glds16(bg + k0, bl0);
    glds16(bg + k0 + K16, bl1);
    __syncthreads();
    bf16x8 af[4], bfv[4];
#pragma unroll
    for (int i = 0; i < 4; ++i) {
      af[i]  = *(const bf16x8*)&As[wr * 4 + i][lane * 8];
      bfv[i] = *(const bf16x8*)&Bs[wc * 4 + i][lane * 8];
    }
#pragma unroll
    for (int mb = 0; mb < 4; ++mb)
#pragma unroll
      for (int nb = 0; nb < 4; ++nb)
        acc[mb][nb] = __builtin_amdgcn_mfma_f32_16x16x32_bf16(
            af[mb], bfv[nb], acc[mb][nb], 0, 0, 0);
  }
#pragma unroll
  for (int mb = 0; mb < 4; ++mb) {
    long row = m0 + wr * 64 + mb * 16 + fq * 4;
#pragma unroll
    for (int nb = 0; nb < 4; ++nb) {
      long col = n0 + wc * 64 + nb * 16 + fr;
#pragma unroll
      for (int i = 0; i < 4; ++i)
        C[(row + i) * (long)N + col] = (TC)acc[mb][nb][i];
    }
  }
}

// ---------------- QKV GEMM: 256x256 8-phase schedule (T2+T3+T4+T5) ----------
// A[8192,1024] * Wqkv_t[3072,1024]^T. BM=BN=256, BK=64, 8 waves (2M x 4N),
// 128 KiB double-buffered LDS in st_16x32-swizzled fragment layout.
// LDS regions per buf: [0]=A rows 0-127, [1]=A rows 128-255, [2]=B rows 0-127,
// [3]=B rows 128-255. Each region 8192 bf16 = 16 KiB, staged as 2 glds/thread
// with the INVERSE swizzle applied to the per-lane global source (rule #21;
// global_load_lds dest is linear wave-uniform+lane*16).
// K-tile j lives in buf j&1. Per-phase staging ledger (one half-tile = 2 glds):
//   p1: A0(j+1)->nb   p2: A1(j+1)->nb   p3: B0(j+2)->b   p4: B1(j+2)->b
// (B regions of buf b are free after p2's closing barrier; A of nb free all
// tile.) Single counted vmcnt(4) at end of p4 ensures all 4 half-tiles of
// tile j+1 resident; 4-12 loads stay in flight, never drained in-loop.
// Quadrants per phase: p1 (fm0-3,fn0-1) p2 (fm0-3,fn2-3) p3 (fm4-7,fn2-3)
// p4 (fm4-7,fn0-1); 16 MFMA each wrapped in setprio(1).
// Epilogue: cols<1024 (Q): *QSCALE -> qk; <2048 (K) -> qk; >=2048 (V):
// transposed u16x4 (4 consecutive tokens) -> vT.
#define QUAD(HM, HN)                                                          \
  do {                                                                        \
    _Pragma("unroll") for (int m2 = 0; m2 < 4; ++m2) {                        \
      _Pragma("unroll") for (int n2 = 0; n2 < 2; ++n2) {                      \
        _Pragma("unroll") for (int kc = 0; kc < 2; ++kc)                      \
            acc[(HM) * 4 + m2][(HN) * 2 + n2] =                               \
                __builtin_amdgcn_mfma_f32_16x16x32_bf16(                      \
                    aF[m2][kc], bF[(HN) * 2 + n2][kc],                        \
                    acc[(HM) * 4 + m2][(HN) * 2 + n2], 0, 0, 0);              \
      }                                                                       \
    }                                                                         \
  } while (0)

__launch_bounds__(512, 2)
__global__ void gemm_qkv(const bf16* __restrict__ A, const bf16* __restrict__ Bt,
                         bf16* __restrict__ qk, bf16* __restrict__ vT) {
  __shared__ __attribute__((aligned(16))) bf16 smem[2][4][8192];  // 128 KiB
  const int K = 1024;                    // 16 K-tiles of 64
  int t = threadIdx.x;                   // 0..511
  int w = t >> 6, lane = t & 63;
  int wm = w >> 2, wn = w & 3;           // 2 x 4 wave grid
  int fr = lane & 15, fq = lane >> 4;
  long m0 = (long)blockIdx.y * 256, n0 = (long)blockIdx.x * 256;

  // ---- staging geometry: thread t covers linear LDS bytes [t*16, t*16+16)
  // of a region (slot r=1 adds 8192B). Source = element logically at the
  // SWIZZLED position (involution), so the swizzled read sees correct data.
  {
  }
  int o = t * 16;
  int p = o ^ (((o >> 9) & 1) << 5);     // st_16x32: bit9 -> bit5
  int si = p >> 10;                      // subtile (i*2+jj), 1 KiB each
  int srow = (si >> 1) * 16 + ((p & 1023) >> 6);  // 0..63 (r=1 adds 64)
  int scol = (si & 1) * 32 + ((p & 63) >> 1);     // 0..63 within K-tile
  const bf16* aS = A  + (m0 + srow) * (long)K + scol;
  const bf16* bS = Bt + (n0 + srow) * (long)K + scol;

  // ---- fragment-read bases (swizzle folds to a lane constant: bit9 = fr&8)
  int fro = (fr << 6) + (fq << 4);
  fro ^= (fr & 8) << 2;
  const char* Afr0 = (const char*)&smem[0][wm][0] + fro;
  const char* Bfr0 = (const char*)&smem[0][2 + (wn >> 1)][0] + ((wn & 1) << 13) + fro;
  bf16* s00 = &smem[0][0][0];

  f32x4 acc[8][4] = {};
  bf16x8 aF[4][2], bF[4][2];

  // one half-tile = 2 glds/thread: r=0 rows srow, r=1 rows srow+64
#define STAGE(src, dstRegion)                          \
  do {                                                 \
    glds16((src), (dstRegion) + w * 512);              \
    glds16((src) + 65536, (dstRegion) + 4096 + w * 512); \
  } while (0)

  // ---- prologue: tile0 all 4 half-tiles, then tile1's B halves (in flight)
  STAGE(aS,               s00);              // A0(0)
  STAGE(aS + 131072,      s00 + 8192);       // A1(0)
  STAGE(bS,               s00 + 16384);      // B0(0)
  STAGE(bS + 131072,      s00 + 24576);      // B1(0)
  STAGE(bS + 64,          s00 + 32768 + 16384);  // B0(1)
  STAGE(bS + 64 + 131072, s00 + 32768 + 24576);  // B1(1)
  VMCNT(4);                                  // first 8 loads (tile 0) done
  MEMFENCE(); BARRIER_RAW(); MEMFENCE();

  for (int j = 0; j < 16; ++j) {
    int b = j & 1, nb = b ^ 1;
    long kA = (long)((j + 1 < 16) ? j + 1 : 15) * 64;
    long kB = (long)((j + 2 < 16) ? j + 2 : 15) * 64;
    const char* Ab = Afr0 + b * 65536;
    const char* Bb = Bfr0 + b * 65536;
    bf16* sA0 = s00 + nb * 32768;
    bf16* sB0 = s00 + b * 32768 + 16384;

    // ---- phase 1: quadrant (0,0); read A fm0-3 + B fn0-1; stage A0(j+1)
#pragma unroll
    for (int m2 = 0; m2 < 4; ++m2)
#pragma unroll
      for (int kc = 0; kc < 2; ++kc)
        aF[m2][kc] = *(const bf16x8*)(Ab + (m2 * 2 + kc) * 1024);
#pragma unroll
    for (int n2 = 0; n2 < 2; ++n2)
#pragma unroll
      for (int kc = 0; kc < 2; ++kc)
        bF[n2][kc] = *(const bf16x8*)(Bb + (n2 * 2 + kc) * 1024);
    STAGE(aS + kA, sA0);
    MEMFENCE(); BARRIER_RAW(); LGKM0();
    __builtin_amdgcn_s_setprio(1);
    QUAD(0, 0);
    __builtin_amdgcn_s_setprio(0);
    MEMFENCE(); BARRIER_RAW(); MEMFENCE();

    // ---- phase 2: quadrant (0,1); read B fn2-3; stage A1(j+1)
#pragma unroll
    for (int n2 = 2; n2 < 4; ++n2)
#pragma unroll
      for (int kc = 0; kc < 2; ++kc)
        bF[n2][kc] = *(const bf16x8*)(Bb + (n2 * 2 + kc) * 1024);
    STAGE(aS + kA + 131072, sA0 + 8192);
    MEMFENCE(); BARRIER_RAW(); LGKM0();
    __builtin_amdgcn_s_setprio(1);
    QUAD(0, 1);
    __builtin_amdgcn_s_setprio(0);
    MEMFENCE(); BARRIER_RAW(); MEMFENCE();

    // ---- phase 3: quadrant (1,1); read A fm4-7; stage B0(j+2)
#pragma unroll
    for (int m2 = 0; m2 < 4; ++m2)
#pragma unroll
      for (int kc = 0; kc < 2; ++kc)
        aF[m2][kc] = *(const bf16x8*)(Ab + ((4 + m2) * 2 + kc) * 1024);
    STAGE(bS + kB, sB0);
    MEMFENCE(); BARRIER_RAW(); LGKM0();
    __builtin_amdgcn_s_setprio(1);
    QUAD(1, 1);
    __builtin_amdgcn_s_setprio(0);
    MEMFENCE(); BARRIER_RAW(); MEMFENCE();

    // ---- phase 4: quadrant (1,0); no reads; stage B1(j+2); counted vmcnt
    STAGE(bS + kB + 131072, sB0 + 8192);
    MEMFENCE(); BARRIER_RAW(); LGKM0();
    __builtin_amdgcn_s_setprio(1);
    QUAD(1, 0);
    __builtin_amdgcn_s_setprio(0);
    VMCNT(4);  // all 4 half-tiles of tile j+1 resident; 2 stay in flight
    MEMFENCE(); BARRIER_RAW(); MEMFENCE();
  }
#undef STAGE

  // ---- epilogue (fused QKV layout)
#pragma unroll
  for (int fm = 0; fm < 8; ++fm) {
    long row = m0 + wm * 128 + fm * 16 + fq * 4;  // token index (global)
    long bb = row >> 11;                          // batch
    long s0 = row & 2047;                         // token within batch
#pragma unroll
    for (int fn = 0; fn < 4; ++fn) {
      long col = n0 + wn * 64 + fn * 16 + fr;
      if (col < 2048) {
        float sc = (col < 1024) ? QSCALE : 1.f;
#pragma unroll
        for (int i = 0; i < 4; ++i)
          qk[(row + i) * 2048 + col] = (bf16)(acc[fm][fn][i] * sc);
      } else {
        u16x4 pk;
#pragma unroll
        for (int i = 0; i < 4; ++i) pk[i] = bf16_bits(acc[fm][fn][i]);
        *(u16x4*)(vT + (bb * 1024 + (col - 2048)) * 2048 + s0) = pk;
      }
    }
  }
}

// ---------------- MFMA flash attention v3 (causal, LDS-diet) ----------------
// grid (8, H, B). Block pr handles 128-row super-tiles {pr, 15-pr} (34 iters
// const). Wave w owns q-rows w*32..w*32+31 (2 strips of 16). Q frags in
// registers; K/V staged fragment-ordered via global_load_lds (V from the
// pre-transposed vT); K/V frag regs reused across both strips. P roundtrip
// through padded conflict-free Pb. Softmax = exp2 (q pre-scaled), l summed
// per-lane, reduced once per super-tile.
__launch_bounds__(256, 2)
__global__ void attn_mfma3(const bf16* __restrict__ qk, const bf16* __restrict__ vT,
                           bf16* __restrict__ out) {
  __shared__ __attribute__((aligned(16))) bf16 Ks[4][2][512];
  __shared__ __attribute__((aligned(16))) bf16 Vs[4][2][512];
  __shared__ __attribute__((aligned(16))) bf16 Pb[4][16][76];  // pad 76: conflict-free
  int pr = blockIdx.x, h = blockIdx.y, b = blockIdx.z;
  int t = threadIdx.x, w = t >> 6, lane = t & 63;
  int fr = lane & 15, fq = lane >> 4;
  const bf16* qkb = qk + (long)b * S_ * 2048;
  const bf16* vTb = vT + ((long)b * 1024 + h * HD_) * 2048;
  bf16* ob = out + (long)b * S_ * D_ + h * HD_;

  for (int half = 0; half < 2; ++half) {
    int st = half ? (15 - pr) : pr;
    int qbase = st * 128 + w * 32;
    // Q fragments for this super-tile (registers, loaded once)
    bf16x8 aQ[2][2];
#pragma unroll
    for (int s = 0; s < 2; ++s)
#pragma unroll
      for (int kc = 0; kc < 2; ++kc)
        aQ[s][kc] = *(const bf16x8*)(qkb + (long)(qbase + s * 16 + fr) * 2048 +
                                     h * HD_ + kc * 32 + fq * 8);
    f32x4 acc_o[2][4] = {};
    float lsum[2][4] = {};
    int jtmax = 2 * st + 1;

    for (int jt = 0; jt <= jtmax; ++jt) {
      __syncthreads();  // prior iter's frag reads done before LDS overwrite
      {  // stage K dim-chunks + V (from vT) — wave w stages block w
        const bf16* kg = qkb + (long)(jt * 64 + w * 16 + fr) * 2048 + 1024 + h * HD_ + fq * 8;
        glds16(kg,      &Ks[w][0][0]);
        glds16(kg + 32, &Ks[w][1][0]);
        const bf16* vg = vTb + (long)(w * 16 + fr) * 2048 + jt * 64 + fq * 8;
        glds16(vg,      &Vs[w][0][0]);
        glds16(vg + 32, &Vs[w][1][0]);
      }
      __syncthreads();
      // fragment regs (reused by both strips)
      bf16x8 bK[4][2], bV[4][2];
#pragma unroll
      for (int nb = 0; nb < 4; ++nb)
#pragma unroll
        for (int kc = 0; kc < 2; ++kc) {
          bK[nb][kc] = *(const bf16x8*)&Ks[nb][kc][lane * 8];
          bV[nb][kc] = *(const bf16x8*)&Vs[nb][kc][lane * 8];
        }
#pragma unroll
      for (int s = 0; s < 2; ++s) {
        int dlim = qbase + s * 16 - jt * 64;  // mask iff key > dlim + (fq*4+i)
        if (dlim <= -16) continue;            // strip fully masked (wave-uniform)
        f32x4 acc_s[4] = {};
#pragma unroll
        for (int nb = 0; nb < 4; ++nb) {
          acc_s[nb] = __builtin_amdgcn_mfma_f32_16x16x32_bf16(aQ[s][0], bK[nb][0], acc_s[nb], 0, 0, 0);
          acc_s[nb] = __builtin_amdgcn_mfma_f32_16x16x32_bf16(aQ[s][1], bK[nb][1], acc_s[nb], 0, 0, 0);
        }
        if (dlim < 63) {  // diagonal strip: apply causal mask
#pragma unroll
          for (int i = 0; i < 4; ++i) {
            int qa = dlim + fq * 4 + i;
#pragma unroll
            for (int nb = 0; nb < 4; ++nb) {
              float pv = exp2f(acc_s[nb][i]);
              if (nb * 16 + fr > qa) pv = 0.f;
              lsum[s][i] += pv;
              Pb[w][fq * 4 + i][nb * 16 + fr] = (bf16)pv;
            }
          }
        } else {
#pragma unroll
          for (int i = 0; i < 4; ++i)
#pragma unroll
            for (int nb = 0; nb < 4; ++nb) {
              float pv = exp2f(acc_s[nb][i]);
              lsum[s][i] += pv;
              Pb[w][fq * 4 + i][nb * 16 + fr] = (bf16)pv;
            }
        }
        // PV: O_s += P(16x64) · V(64x64)^T^T  (Pb wave-private, in-order LDS)
#pragma unroll
        for (int kc = 0; kc < 2; ++kc) {
          bf16x8 aP = *(const bf16x8*)&Pb[w][fr][kc * 32 + fq * 8];
#pragma unroll
          for (int nb = 0; nb < 4; ++nb)
            acc_o[s][nb] = __builtin_amdgcn_mfma_f32_16x16x32_bf16(aP, bV[nb][kc], acc_o[s][nb], 0, 0, 0);
        }
      }
    }
    // epilogue: reduce l over the 16 fr-lanes, normalize, store
#pragma unroll
    for (int s = 0; s < 2; ++s) {
      long r0 = (long)(qbase + s * 16 + fq * 4);
#pragma unroll
      for (int i = 0; i < 4; ++i) {
        float l = lsum[s][i];
#pragma unroll
        for (int d = 1; d < 16; d <<= 1) l += __shfl_xor(l, d, 16);
        float inv = 1.f / l;
#pragma unroll
        for (int nb = 0; nb < 4; ++nb)
          ob[(r0 + i) * D_ + nb * 16 + fr] = (bf16)(acc_o[s][nb][i] * inv);
      }
    }
  }
}

// ---------------- sentinel (diagnostic) ----------------
__global__ void sentinel_k(float* out, float v, int n) {
  int i = blockIdx.x * 256 + threadIdx.x;
  if (i < n) out[i] = v;
}

// ---------------- launch ----------------
// ws (75,497,472 B — confirmed available):
//   qk     [8192][2048] bf16  33.55 MB   (Q scaled | K)
//   vT     [4][1024][2048]    16.78 MB   (V transposed per batch/head-dim)
//   x_bf   [8192][1024]       16.78 MB   (reused as ao after gemm_qkv)
//   wqkv_t [3072][1024]        6.29 MB
//   wout_t [1024][1024]        2.10 MB
extern "C" void kernel_launch(void* const* d_in, const int* in_sizes, int n_in,
                              void* d_out, int out_size, void* d_ws, size_t ws_size,
                              hipStream_t stream) {
  const float* x    = (const float*)d_in[0];
  // d_in[1] = causal mask (tril) — structure known, not read.
  const float* Wqkv = (const float*)d_in[2];
  const float* Wout = (const float*)d_in[3];
  float* out = (float*)d_out;

  const size_t SD = (size_t)S_ * D_;
  bf16* qk     = (bf16*)d_ws;                    // 16777216 elems
  bf16* vT     = qk + (size_t)8192 * 2048;       //  8388608 elems
  bf16* x_bf   = vT + (size_t)4 * 1024 * 2048;   //  8388608 elems (→ ao)
  bf16* ao     = x_bf;
  bf16* wqkv_t = x_bf + (size_t)8192 * 1024;     //  3145728 elems
  bf16* wout_t = wqkv_t + (size_t)3072 * 1024;   //  1048576 elems
  size_t need = ((size_t)16777216 + 8388608 + 8388608 + 3145728 + 1048576) * sizeof(bf16);

  if (ws_size >= need) {
    cvt_x<<<4096, 256, 0, stream>>>(x, x_bf, (long)(B_ * SD));
    cvt_w<<<dim3(3072 / 32, 1024 / 32), dim3(32, 8), 0, stream>>>(Wqkv, wqkv_t, 1024, 3072);
    cvt_w<<<dim3(1024 / 32, 1024 / 32), dim3(32, 8), 0, stream>>>(Wout, wout_t, 1024, 1024);
    gemm_qkv<<<dim3(3072 / 256, (B_ * S_) / 256), 512, 0, stream>>>(
        x_bf, wqkv_t, qk, vT);
    attn_mfma3<<<dim3(8, H_, B_), 256, 0, stream>>>(qk, vT, ao);
    gemm128<float><<<dim3(D_ / 128, (B_ * S_) / 128), 256, 0, stream>>>(
        ao, wout_t, out, B_ * S_, D_, D_);
  } else {
    float v = 1000.f + (float)(ws_size >> 20);
    int n = (int)((size_t)B_ * SD);
    sentinel_k<<<(n + 255) / 256, 256, 0, stream>>>(out, v, n);
  }
}

// Round 2
// 295.994 us; speedup vs baseline: 1.1264x; 1.0107x over previous
//
#include <hip/hip_runtime.h>
#include <hip/hip_bf16.h>

typedef __bf16 bf16;
typedef unsigned short u16;
typedef unsigned int u32;
typedef __attribute__((ext_vector_type(8))) __bf16 bf16x8;
typedef __attribute__((ext_vector_type(4))) unsigned short u16x4;
typedef __attribute__((ext_vector_type(4))) float f32x4;

#define B_  4
#define S_  2048
#define D_  1024
#define H_  16
#define HD_ 64

// 0.125 * log2(e): folded into q so softmax is exp2(acc) directly
#define QSCALE 0.18033688f

__device__ inline u16 bf16_bits(float f) {
  bf16 h = (bf16)f;
  return __builtin_bit_cast(u16, h);
}

__device__ __forceinline__ void glds16(const bf16* g, bf16* s) {
  __builtin_amdgcn_global_load_lds(
      (const __attribute__((address_space(1))) void*)g,
      (__attribute__((address_space(3))) void*)s, 16, 0, 0);
}

#define MEMFENCE() asm volatile("" ::: "memory")
#define BARRIER_RAW() __builtin_amdgcn_s_barrier()
#define LGKM0() asm volatile("s_waitcnt lgkmcnt(0)" ::: "memory")
#define VMCNT(n) asm volatile("s_waitcnt vmcnt(" #n ")" ::: "memory")

// ---------------- converters ----------------
__global__ void cvt_x(const float* __restrict__ in, bf16* __restrict__ out, long n) {
  long i = ((long)blockIdx.x * 256 + threadIdx.x) * 8;
  if (i < n) {
    f32x4 a = *(const f32x4*)(in + i);
    f32x4 b = *(const f32x4*)(in + i + 4);
    bf16x8 v;
#pragma unroll
    for (int j = 0; j < 4; ++j) { v[j] = (bf16)a[j]; v[4 + j] = (bf16)b[j]; }
    *(bf16x8*)(out + i) = v;
  }
}

// f32 [K][N] -> bf16 [N][K] (transpose + convert)
__global__ void cvt_w(const float* __restrict__ in, bf16* __restrict__ out,
                      int K, int N) {
  __shared__ float tile[32][33];
  int n0 = blockIdx.x * 32, k0 = blockIdx.y * 32;
  int x = threadIdx.x, y = threadIdx.y;  // block (32,8)
#pragma unroll
  for (int i = 0; i < 32; i += 8)
    tile[y + i][x] = in[(long)(k0 + y + i) * N + (n0 + x)];
  __syncthreads();
#pragma unroll
  for (int i = 0; i < 32; i += 8)
    out[(long)(n0 + y + i) * K + (k0 + x)] = (bf16)tile[x][y + i];
}

// ---------------- m97-structure GEMM core (128x128 tile) --------------------
// Kept for the attention-out projection (grid 512 blocks there).
template <typename TC>
__launch_bounds__(256)
__global__ void gemm128(const bf16* __restrict__ A, const bf16* __restrict__ Bt,
                        TC* __restrict__ C, int M, int N, int K) {
  __shared__ __attribute__((aligned(16))) bf16 As[8][512];
  __shared__ __attribute__((aligned(16))) bf16 Bs[8][512];
  int t = threadIdx.x;
  int w = t >> 6, lane = t & 63;
  int wr = w >> 1, wc = w & 1;
  int fr = lane & 15, fq = lane >> 4;
  long m0 = (long)blockIdx.y * 128, n0 = (long)blockIdx.x * 128;
  f32x4 acc[4][4] = {};
  const bf16* ag = A  + (m0 + (2 * w) * 16 + fr) * (long)K + fq * 8;
  const bf16* bg = Bt + (n0 + (2 * w) * 16 + fr) * (long)K + fq * 8;
  bf16* al0 = &As[2 * w][0];
  bf16* al1 = &As[2 * w + 1][0];
  bf16* bl0 = &Bs[2 * w][0];
  bf16* bl1 = &Bs[2 * w + 1][0];
  const long K16 = 16 * (long)K;
  for (int k0 = 0; k0 < K; k0 += 32) {
    __syncthreads();
    glds16(ag + k0, al0);
    glds16(ag + k0 + K16, al1);
    glds16(bg + k0, bl0);
    glds16(bg + k0 + K16, bl1);
    __syncthreads();
    bf16x8 af[4], bfv[4];
#pragma unroll
    for (int i = 0; i < 4; ++i) {
      af[i]  = *(const bf16x8*)&As[wr * 4 + i][lane * 8];
      bfv[i] = *(const bf16x8*)&Bs[wc * 4 + i][lane * 8];
    }
#pragma unroll
    for (int mb = 0; mb < 4; ++mb)
#pragma unroll
      for (int nb = 0; nb < 4; ++nb)
        acc[mb][nb] = __builtin_amdgcn_mfma_f32_16x16x32_bf16(
            af[mb], bfv[nb], acc[mb][nb], 0, 0, 0);
  }
#pragma unroll
  for (int mb = 0; mb < 4; ++mb) {
    long row = m0 + wr * 64 + mb * 16 + fq * 4;
#pragma unroll
    for (int nb = 0; nb < 4; ++nb) {
      long col = n0 + wc * 64 + nb * 16 + fr;
#pragma unroll
      for (int i = 0; i < 4; ++i)
        C[(row + i) * (long)N + col] = (TC)acc[mb][nb][i];
    }
  }
}

// ---------------- QKV GEMM: 256x256 8-phase schedule (T2+T3+T4+T5) ----------
// (unchanged from round 1 — verified, gemm_qkv fell out of the top-5)
#define QUAD(HM, HN)                                                          \
  do {                                                                        \
    _Pragma("unroll") for (int m2 = 0; m2 < 4; ++m2) {                        \
      _Pragma("unroll") for (int n2 = 0; n2 < 2; ++n2) {                      \
        _Pragma("unroll") for (int kc = 0; kc < 2; ++kc)                      \
            acc[(HM) * 4 + m2][(HN) * 2 + n2] =                               \
                __builtin_amdgcn_mfma_f32_16x16x32_bf16(                      \
                    aF[m2][kc], bF[(HN) * 2 + n2][kc],                        \
                    acc[(HM) * 4 + m2][(HN) * 2 + n2], 0, 0, 0);              \
      }                                                                       \
    }                                                                         \
  } while (0)

__launch_bounds__(512, 2)
__global__ void gemm_qkv(const bf16* __restrict__ A, const bf16* __restrict__ Bt,
                         bf16* __restrict__ qk, bf16* __restrict__ vT) {
  __shared__ __attribute__((aligned(16))) bf16 smem[2][4][8192];  // 128 KiB
  const int K = 1024;                    // 16 K-tiles of 64
  int t = threadIdx.x;                   // 0..511
  int w = t >> 6, lane = t & 63;
  int wm = w >> 2, wn = w & 3;           // 2 x 4 wave grid
  int fr = lane & 15, fq = lane >> 4;
  long m0 = (long)blockIdx.y * 256, n0 = (long)blockIdx.x * 256;

  int o = t * 16;
  int p = o ^ (((o >> 9) & 1) << 5);     // st_16x32: bit9 -> bit5
  int si = p >> 10;                      // subtile (i*2+jj), 1 KiB each
  int srow = (si >> 1) * 16 + ((p & 1023) >> 6);  // 0..63 (r=1 adds 64)
  int scol = (si & 1) * 32 + ((p & 63) >> 1);     // 0..63 within K-tile
  const bf16* aS = A  + (m0 + srow) * (long)K + scol;
  const bf16* bS = Bt + (n0 + srow) * (long)K + scol;

  // ---- fragment-read bases (swizzle folds to a lane constant: bit9 = fr&8)
  int fro = (fr << 6) + (fq << 4);
  fro ^= (fr & 8) << 2;
  const char* Afr0 = (const char*)&smem[0][wm][0] + fro;
  const char* Bfr0 = (const char*)&smem[0][2 + (wn >> 1)][0] + ((wn & 1) << 13) + fro;
  bf16* s00 = &smem[0][0][0];

  f32x4 acc[8][4] = {};
  bf16x8 aF[4][2], bF[4][2];

#define STAGE(src, dstRegion)                          \
  do {                                                 \
    glds16((src), (dstRegion) + w * 512);              \
    glds16((src) + 65536, (dstRegion) + 4096 + w * 512); \
  } while (0)

  // ---- prologue: tile0 all 4 half-tiles, then tile1's B halves (in flight)
  STAGE(aS,               s00);              // A0(0)
  STAGE(aS + 131072,      s00 + 8192);       // A1(0)
  STAGE(bS,               s00 + 16384);      // B0(0)
  STAGE(bS + 131072,      s00 + 24576);      // B1(0)
  STAGE(bS + 64,          s00 + 32768 + 16384);  // B0(1)
  STAGE(bS + 64 + 131072, s00 + 32768 + 24576);  // B1(1)
  VMCNT(4);                                  // first 8 loads (tile 0) done
  MEMFENCE(); BARRIER_RAW(); MEMFENCE();

  for (int j = 0; j < 16; ++j) {
    int b = j & 1, nb = b ^ 1;
    long kA = (long)((j + 1 < 16) ? j + 1 : 15) * 64;
    long kB = (long)((j + 2 < 16) ? j + 2 : 15) * 64;
    const char* Ab = Afr0 + b * 65536;
    const char* Bb = Bfr0 + b * 65536;
    bf16* sA0 = s00 + nb * 32768;
    bf16* sB0 = s00 + b * 32768 + 16384;

    // ---- phase 1: quadrant (0,0); read A fm0-3 + B fn0-1; stage A0(j+1)
#pragma unroll
    for (int m2 = 0; m2 < 4; ++m2)
#pragma unroll
      for (int kc = 0; kc < 2; ++kc)
        aF[m2][kc] = *(const bf16x8*)(Ab + (m2 * 2 + kc) * 1024);
#pragma unroll
    for (int n2 = 0; n2 < 2; ++n2)
#pragma unroll
      for (int kc = 0; kc < 2; ++kc)
        bF[n2][kc] = *(const bf16x8*)(Bb + (n2 * 2 + kc) * 1024);
    STAGE(aS + kA, sA0);
    MEMFENCE(); BARRIER_RAW(); LGKM0();
    __builtin_amdgcn_s_setprio(1);
    QUAD(0, 0);
    __builtin_amdgcn_s_setprio(0);
    MEMFENCE(); BARRIER_RAW(); MEMFENCE();

    // ---- phase 2: quadrant (0,1); read B fn2-3; stage A1(j+1)
#pragma unroll
    for (int n2 = 2; n2 < 4; ++n2)
#pragma unroll
      for (int kc = 0; kc < 2; ++kc)
        bF[n2][kc] = *(const bf16x8*)(Bb + (n2 * 2 + kc) * 1024);
    STAGE(aS + kA + 131072, sA0 + 8192);
    MEMFENCE(); BARRIER_RAW(); LGKM0();
    __builtin_amdgcn_s_setprio(1);
    QUAD(0, 1);
    __builtin_amdgcn_s_setprio(0);
    MEMFENCE(); BARRIER_RAW(); MEMFENCE();

    // ---- phase 3: quadrant (1,1); read A fm4-7; stage B0(j+2)
#pragma unroll
    for (int m2 = 0; m2 < 4; ++m2)
#pragma unroll
      for (int kc = 0; kc < 2; ++kc)
        aF[m2][kc] = *(const bf16x8*)(Ab + ((4 + m2) * 2 + kc) * 1024);
    STAGE(bS + kB, sB0);
    MEMFENCE(); BARRIER_RAW(); LGKM0();
    __builtin_amdgcn_s_setprio(1);
    QUAD(1, 1);
    __builtin_amdgcn_s_setprio(0);
    MEMFENCE(); BARRIER_RAW(); MEMFENCE();

    // ---- phase 4: quadrant (1,0); no reads; stage B1(j+2); counted vmcnt
    STAGE(bS + kB + 131072, sB0 + 8192);
    MEMFENCE(); BARRIER_RAW(); LGKM0();
    __builtin_amdgcn_s_setprio(1);
    QUAD(1, 0);
    __builtin_amdgcn_s_setprio(0);
    VMCNT(4);  // all 4 half-tiles of tile j+1 resident; 2 stay in flight
    MEMFENCE(); BARRIER_RAW(); MEMFENCE();
  }
#undef STAGE

  // ---- epilogue (fused QKV layout)
#pragma unroll
  for (int fm = 0; fm < 8; ++fm) {
    long row = m0 + wm * 128 + fm * 16 + fq * 4;  // token index (global)
    long bb = row >> 11;                          // batch
    long s0 = row & 2047;                         // token within batch
#pragma unroll
    for (int fn = 0; fn < 4; ++fn) {
      long col = n0 + wn * 64 + fn * 16 + fr;
      if (col < 2048) {
        float sc = (col < 1024) ? QSCALE : 1.f;
#pragma unroll
        for (int i = 0; i < 4; ++i)
          qk[(row + i) * 2048 + col] = (bf16)(acc[fm][fn][i] * sc);
      } else {
        u16x4 pk;
#pragma unroll
        for (int i = 0; i < 4; ++i) pk[i] = bf16_bits(acc[fm][fn][i]);
        *(u16x4*)(vT + (bb * 1024 + (col - 2048)) * 2048 + s0) = pk;
      }
    }
  }
}

// ---------------- MFMA flash attention v4 (causal, 2-phase pipelined) -------
// grid (8, H, B). Block pr handles 128-row super-tiles {pr, 15-pr} (34 iters
// const). Wave w owns q-rows w*32..w*32+31 (2 strips of 16). Q frags in
// registers; K/V DOUBLE-BUFFERED in LDS, staged via global_load_lds with the
// next tile issued right after the single per-iter barrier (loads in flight
// across the whole compute phase; __syncthreads' implicit vmcnt(0) drain at
// the next iter top is the counted wait). Softmax = exp2 (q pre-scaled);
// row-sum l computed by an extra ones-MFMA per P-slice (acc_l) instead of
// 32 scalar fadds — epilogue needs no shuffle reduce.
__launch_bounds__(256, 2)
__global__ void attn_mfma3(const bf16* __restrict__ qk, const bf16* __restrict__ vT,
                           bf16* __restrict__ out) {
  __shared__ __attribute__((aligned(16))) bf16 Ks[2][4][2][512];
  __shared__ __attribute__((aligned(16))) bf16 Vs[2][4][2][512];
  __shared__ __attribute__((aligned(16))) bf16 Pb[4][16][76];  // pad 76: conflict-free
  int pr = blockIdx.x, h = blockIdx.y, b = blockIdx.z;
  int t = threadIdx.x, w = t >> 6, lane = t & 63;
  int fr = lane & 15, fq = lane >> 4;
  const bf16* qkb = qk + (long)b * S_ * 2048;
  const bf16* vTb = vT + ((long)b * 1024 + h * HD_) * 2048;
  bf16* ob = out + (long)b * S_ * D_ + h * HD_;

  bf16x8 ones;
#pragma unroll
  for (int j = 0; j < 8; ++j) ones[j] = (bf16)1.0f;

  // per-wave staging source bases (jt=0); stage for tile jt adds jt*64 keys
  const bf16* kg0 = qkb + (long)(w * 16 + fr) * 2048 + 1024 + h * HD_ + fq * 8;
  const bf16* vg0 = vTb + (long)(w * 16 + fr) * 2048 + fq * 8;

  for (int half = 0; half < 2; ++half) {
    int st = half ? (15 - pr) : pr;
    int qbase = st * 128 + w * 32;
    int jtmax = 2 * st + 1;

    __syncthreads();  // all waves' reads of prior half's buffers retired
    // prologue: stage tile 0 -> buf 0 (wave w stages region w)
    glds16(kg0,      &Ks[0][w][0][0]);
    glds16(kg0 + 32, &Ks[0][w][1][0]);
    glds16(vg0,      &Vs[0][w][0][0]);
    glds16(vg0 + 32, &Vs[0][w][1][0]);

    // Q fragments for this super-tile (registers, loaded once)
    bf16x8 aQ[2][2];
#pragma unroll
    for (int s = 0; s < 2; ++s)
#pragma unroll
      for (int kc = 0; kc < 2; ++kc)
        aQ[s][kc] = *(const bf16x8*)(qkb + (long)(qbase + s * 16 + fr) * 2048 +
                                     h * HD_ + kc * 32 + fq * 8);
    f32x4 acc_o[2][4] = {};
    f32x4 acc_l[2] = {};

    for (int jt = 0; jt <= jtmax; ++jt) {
      int c = jt & 1;
      // implicit vmcnt(0) drain (our tile-jt loads) + global barrier:
      __syncthreads();
      if (jt < jtmax) {  // issue next tile early; in flight across compute
        int n = c ^ 1;
        const bf16* kg = kg0 + (long)(jt + 1) * 64 * 2048;
        const bf16* vg = vg0 + (jt + 1) * 64;
        glds16(kg,      &Ks[n][w][0][0]);
        glds16(kg + 32, &Ks[n][w][1][0]);
        glds16(vg,      &Vs[n][w][0][0]);
        glds16(vg + 32, &Vs[n][w][1][0]);
      }
      // fragment regs (reused by both strips)
      bf16x8 bK[4][2], bV[4][2];
#pragma unroll
      for (int nb = 0; nb < 4; ++nb)
#pragma unroll
        for (int kc = 0; kc < 2; ++kc) {
          bK[nb][kc] = *(const bf16x8*)&Ks[c][nb][kc][lane * 8];
          bV[nb][kc] = *(const bf16x8*)&Vs[c][nb][kc][lane * 8];
        }
#pragma unroll
      for (int s = 0; s < 2; ++s) {
        int dlim = qbase + s * 16 - jt * 64;  // mask iff key > dlim + (fq*4+i)
        if (dlim <= -16) continue;            // strip fully masked (wave-uniform)
        f32x4 acc_s[4] = {};
#pragma unroll
        for (int nb = 0; nb < 4; ++nb) {
          acc_s[nb] = __builtin_amdgcn_mfma_f32_16x16x32_bf16(aQ[s][0], bK[nb][0], acc_s[nb], 0, 0, 0);
          acc_s[nb] = __builtin_amdgcn_mfma_f32_16x16x32_bf16(aQ[s][1], bK[nb][1], acc_s[nb], 0, 0, 0);
        }
        if (dlim < 63) {  // diagonal strip: apply causal mask
#pragma unroll
          for (int i = 0; i < 4; ++i) {
            int qa = dlim + fq * 4 + i;
#pragma unroll
            for (int nb = 0; nb < 4; ++nb) {
              float pv = exp2f(acc_s[nb][i]);
              if (nb * 16 + fr > qa) pv = 0.f;
              Pb[w][fq * 4 + i][nb * 16 + fr] = (bf16)pv;
            }
          }
        } else {
#pragma unroll
          for (int i = 0; i < 4; ++i)
#pragma unroll
            for (int nb = 0; nb < 4; ++nb) {
              float pv = exp2f(acc_s[nb][i]);
              Pb[w][fq * 4 + i][nb * 16 + fr] = (bf16)pv;
            }
        }
        // PV: O_s += P(16x64) · V(64x64)^T^T; l += P · 1 (ones-MFMA row-sum)
#pragma unroll
        for (int kc = 0; kc < 2; ++kc) {
          bf16x8 aP = *(const bf16x8*)&Pb[w][fr][kc * 32 + fq * 8];
          acc_l[s] = __builtin_amdgcn_mfma_f32_16x16x32_bf16(aP, ones, acc_l[s], 0, 0, 0);
#pragma unroll
          for (int nb = 0; nb < 4; ++nb)
            acc_o[s][nb] = __builtin_amdgcn_mfma_f32_16x16x32_bf16(aP, bV[nb][kc], acc_o[s][nb], 0, 0, 0);
        }
      }
    }
    // epilogue: acc_l holds the full 64*ntiles-key row sum (uniform over fr)
#pragma unroll
    for (int s = 0; s < 2; ++s) {
      long r0 = (long)(qbase + s * 16 + fq * 4);
#pragma unroll
      for (int i = 0; i < 4; ++i) {
        float inv = 1.f / acc_l[s][i];
#pragma unroll
        for (int nb = 0; nb < 4; ++nb)
          ob[(r0 + i) * D_ + nb * 16 + fr] = (bf16)(acc_o[s][nb][i] * inv);
      }
    }
  }
}

// ---------------- sentinel (diagnostic) ----------------
__global__ void sentinel_k(float* out, float v, int n) {
  int i = blockIdx.x * 256 + threadIdx.x;
  if (i < n) out[i] = v;
}

// ---------------- launch ----------------
// ws (75,497,472 B — confirmed available):
//   qk     [8192][2048] bf16  33.55 MB   (Q scaled | K)
//   vT     [4][1024][2048]    16.78 MB   (V transposed per batch/head-dim)
//   x_bf   [8192][1024]       16.78 MB   (reused as ao after gemm_qkv)
//   wqkv_t [3072][1024]        6.29 MB
//   wout_t [1024][1024]        2.10 MB
extern "C" void kernel_launch(void* const* d_in, const int* in_sizes, int n_in,
                              void* d_out, int out_size, void* d_ws, size_t ws_size,
                              hipStream_t stream) {
  const float* x    = (const float*)d_in[0];
  // d_in[1] = causal mask (tril) — structure known, not read.
  const float* Wqkv = (const float*)d_in[2];
  const float* Wout = (const float*)d_in[3];
  float* out = (float*)d_out;

  const size_t SD = (size_t)S_ * D_;
  bf16* qk     = (bf16*)d_ws;                    // 16777216 elems
  bf16* vT     = qk + (size_t)8192 * 2048;       //  8388608 elems
  bf16* x_bf   = vT + (size_t)4 * 1024 * 2048;   //  8388608 elems (→ ao)
  bf16* ao     = x_bf;
  bf16* wqkv_t = x_bf + (size_t)8192 * 1024;     //  3145728 elems
  bf16* wout_t = wqkv_t + (size_t)3072 * 1024;   //  1048576 elems
  size_t need = ((size_t)16777216 + 8388608 + 8388608 + 3145728 + 1048576) * sizeof(bf16);

  if (ws_size >= need) {
    cvt_x<<<4096, 256, 0, stream>>>(x, x_bf, (long)(B_ * SD));
    cvt_w<<<dim3(3072 / 32, 1024 / 32), dim3(32, 8), 0, stream>>>(Wqkv, wqkv_t, 1024, 3072);
    cvt_w<<<dim3(1024 / 32, 1024 / 32), dim3(32, 8), 0, stream>>>(Wout, wout_t, 1024, 1024);
    gemm_qkv<<<dim3(3072 / 256, (B_ * S_) / 256), 512, 0, stream>>>(
        x_bf, wqkv_t, qk, vT);
    attn_mfma3<<<dim3(8, H_, B_), 256, 0, stream>>>(qk, vT, ao);
    gemm128<float><<<dim3(D_ / 128, (B_ * S_) / 128), 256, 0, stream>>>(
        ao, wout_t, out, B_ * S_, D_, D_);
  } else {
    float v = 1000.f + (float)(ws_size >> 20);
    int n = (int)((size_t)B_ * SD);
    sentinel_k<<<(n + 255) / 256, 256, 0, stream>>>(out, v, n);
  }
}